// Round 1
// baseline (77.560 us; speedup 1.0000x reference)
//
#include <hip/hip_runtime.h>
#include <math.h>

// Stable softplus: log(1+e^x) = max(x,0) + log(1 + e^-|x|)
__device__ __forceinline__ float sp(float x) {
    float a = fabsf(x);
    float e = __expf(-a);          // v_exp_f32 based, e in (0,1]
    float l = __logf(1.0f + e);    // arg in (1,2], well-conditioned
    return fmaxf(x, 0.0f) + l;
}
__device__ __forceinline__ float sigm(float x) {
    return 1.0f / (1.0f + __expf(-x));
}

// Single-thread kernel: energy at identity + scalar h_s with H = h_s * I.
// At F=I: x = [trC,J,-J,I2] = [3,1,-1,3]; dX/dF = [2I, I, -I, 4I] (exact).
__global__ void setup_kernel(const float* __restrict__ W0, const float* __restrict__ b0,
                             const float* __restrict__ Wh, const float* __restrict__ bh,
                             const float* __restrict__ Wf, const float* __restrict__ bf,
                             float* __restrict__ ws) {
    if (threadIdx.x != 0 || blockIdx.x != 0) return;
    float x[4] = {3.f, 1.f, -1.f, 3.f};
    float zin[5], h[5], zh[4][5];
    for (int j = 0; j < 5; ++j) {
        float z = b0[j];
        for (int m = 0; m < 4; ++m) z += x[m] * W0[m * 5 + j];
        zin[j] = z; h[j] = sp(z);
    }
    for (int i = 0; i < 4; ++i) {
        float hn[5];
        for (int j = 0; j < 5; ++j) {
            float z = bh[i * 5 + j];
            for (int k = 0; k < 5; ++k) z += h[k] * Wh[i * 25 + k * 5 + j];
            zh[i][j] = z; hn[j] = sp(z);
        }
        for (int j = 0; j < 5; ++j) h[j] = hn[j];
    }
    float zf = bf[0];
    for (int k = 0; k < 5; ++k) zf += h[k] * Wf[k];
    float e_id = sp(zf);
    // hand backprop to input x
    float d[5];
    float szf = sigm(zf);
    for (int k = 0; k < 5; ++k) d[k] = Wf[k] * szf;       // grad wrt h4
    for (int i = 3; i >= 0; --i) {
        float dz[5];
        for (int j = 0; j < 5; ++j) dz[j] = d[j] * sigm(zh[i][j]);
        for (int k = 0; k < 5; ++k) {
            float acc = 0.f;
            for (int j = 0; j < 5; ++j) acc += Wh[i * 25 + k * 5 + j] * dz[j];
            d[k] = acc;
        }
    }
    float dz0[5], g[4];
    for (int j = 0; j < 5; ++j) dz0[j] = d[j] * sigm(zin[j]);
    for (int m = 0; m < 4; ++m) {
        float acc = 0.f;
        for (int j = 0; j < 5; ++j) acc += W0[m * 5 + j] * dz0[j];
        g[m] = acc;
    }
    float h_s = -(2.f * g[0] + g[1] - g[2] + 4.f * g[3]);
    ws[0] = e_id;
    ws[1] = h_s;
}

__global__ __launch_bounds__(256) void main_kernel(
        const float* __restrict__ F,
        const float* __restrict__ W0, const float* __restrict__ b0,
        const float* __restrict__ Wh, const float* __restrict__ bh,
        const float* __restrict__ Wf, const float* __restrict__ bf,
        const float* __restrict__ cs,   // [e_id, h_s]
        float* __restrict__ out, int n) {
    int i = blockIdx.x * blockDim.x + threadIdx.x;
    if (i >= n) return;
    const float* f = F + (size_t)i * 9;
    float f0 = f[0], f1 = f[1], f2 = f[2];
    float f3 = f[3], f4 = f[4], f5 = f[5];
    float f6 = f[6], f7 = f[7], f8 = f[8];
    // C = F^T F (symmetric)
    float c00 = f0 * f0 + f3 * f3 + f6 * f6;
    float c11 = f1 * f1 + f4 * f4 + f7 * f7;
    float c22 = f2 * f2 + f5 * f5 + f8 * f8;
    float c01 = f0 * f1 + f3 * f4 + f6 * f7;
    float c02 = f0 * f2 + f3 * f5 + f6 * f8;
    float c12 = f1 * f2 + f4 * f5 + f7 * f8;
    float trC  = c00 + c11 + c22;
    float trC2 = c00 * c00 + c11 * c11 + c22 * c22
               + 2.f * (c01 * c01 + c02 * c02 + c12 * c12);
    float I2 = 0.5f * (trC * trC - trC2);
    float J  = f0 * (f4 * f8 - f5 * f7)
             - f1 * (f3 * f8 - f5 * f6)
             + f2 * (f3 * f7 - f4 * f6);
    // MLP: x = [trC, J, -J, I2]; fold the J and -J rows together.
    float h[5];
    #pragma unroll
    for (int j = 0; j < 5; ++j) {
        float z = b0[j] + trC * W0[j] + J * (W0[5 + j] - W0[10 + j]) + I2 * W0[15 + j];
        h[j] = sp(z);
    }
    #pragma unroll
    for (int l = 0; l < 4; ++l) {
        float hn[5];
        #pragma unroll
        for (int j = 0; j < 5; ++j) {
            float z = bh[l * 5 + j];
            #pragma unroll
            for (int k = 0; k < 5; ++k) z = fmaf(h[k], Wh[l * 25 + k * 5 + j], z);
            hn[j] = sp(z);
        }
        #pragma unroll
        for (int j = 0; j < 5; ++j) h[j] = hn[j];
    }
    float zf = bf[0];
    #pragma unroll
    for (int k = 0; k < 5; ++k) zf = fmaf(h[k], Wf[k], zf);
    float e = sp(zf);
    out[i] = (e - cs[0]) + cs[1] * 0.5f * (trC - 3.0f);
}

extern "C" void kernel_launch(void* const* d_in, const int* in_sizes, int n_in,
                              void* d_out, int out_size, void* d_ws, size_t ws_size,
                              hipStream_t stream) {
    const float* F  = (const float*)d_in[0];
    const float* W0 = (const float*)d_in[1];
    const float* b0 = (const float*)d_in[2];
    const float* Wh = (const float*)d_in[3];
    const float* bh = (const float*)d_in[4];
    const float* Wf = (const float*)d_in[5];
    const float* bf = (const float*)d_in[6];
    float* out = (float*)d_out;
    float* ws  = (float*)d_ws;
    int n = in_sizes[0] / 9;
    setup_kernel<<<1, 64, 0, stream>>>(W0, b0, Wh, bh, Wf, bf, ws);
    int block = 256;
    int grid = (n + block - 1) / block;
    main_kernel<<<grid, block, 0, stream>>>(F, W0, b0, Wh, bh, Wf, bf, ws, out, n);
}

// Round 2
// 63.989 us; speedup vs baseline: 1.2121x; 1.2121x over previous
//
#include <hip/hip_runtime.h>
#include <math.h>

typedef float v4 __attribute__((ext_vector_type(4)));

// Stable softplus: log(1+e^x) = max(x,0) + log(1 + e^-|x|)
__device__ __forceinline__ float spf(float x) {
    float a = fabsf(x);
    float e = __expf(-a);
    float l = __logf(1.0f + e);
    return fmaxf(x, 0.0f) + l;
}
__device__ __forceinline__ float sigm(float x) {
    return 1.0f / (1.0f + __expf(-x));
}
__device__ __forceinline__ v4 splat(float s) { v4 r; r.x = s; r.y = s; r.z = s; r.w = s; return r; }
__device__ __forceinline__ v4 sp4(v4 x) {
    v4 r; r.x = spf(x.x); r.y = spf(x.y); r.z = spf(x.z); r.w = spf(x.w); return r;
}
__device__ __forceinline__ v4 vfma(v4 a, float b, v4 c) {
    return __builtin_elementwise_fma(a, splat(b), c);
}

// Single-thread kernel: energy at identity + scalar h_s with H = h_s * I.
// At F=I: x = [trC,J,-J,I2] = [3,1,-1,3]; dX/dF = [2I, I, -I, 4I] (exact zeros off-diag).
__global__ void setup_kernel(const float* __restrict__ W0, const float* __restrict__ b0,
                             const float* __restrict__ Wh, const float* __restrict__ bh,
                             const float* __restrict__ Wf, const float* __restrict__ bf,
                             float* __restrict__ ws) {
    if (threadIdx.x != 0 || blockIdx.x != 0) return;
    float x[4] = {3.f, 1.f, -1.f, 3.f};
    float zin[5], h[5], zh[4][5];
    for (int j = 0; j < 5; ++j) {
        float z = b0[j];
        for (int m = 0; m < 4; ++m) z += x[m] * W0[m * 5 + j];
        zin[j] = z; h[j] = spf(z);
    }
    for (int i = 0; i < 4; ++i) {
        float hn[5];
        for (int j = 0; j < 5; ++j) {
            float z = bh[i * 5 + j];
            for (int k = 0; k < 5; ++k) z += h[k] * Wh[i * 25 + k * 5 + j];
            zh[i][j] = z; hn[j] = spf(z);
        }
        for (int j = 0; j < 5; ++j) h[j] = hn[j];
    }
    float zf = bf[0];
    for (int k = 0; k < 5; ++k) zf += h[k] * Wf[k];
    float e_id = spf(zf);
    // hand backprop to input x
    float d[5];
    float szf = sigm(zf);
    for (int k = 0; k < 5; ++k) d[k] = Wf[k] * szf;
    for (int i = 3; i >= 0; --i) {
        float dz[5];
        for (int j = 0; j < 5; ++j) dz[j] = d[j] * sigm(zh[i][j]);
        for (int k = 0; k < 5; ++k) {
            float acc = 0.f;
            for (int j = 0; j < 5; ++j) acc += Wh[i * 25 + k * 5 + j] * dz[j];
            d[k] = acc;
        }
    }
    float dz0[5], g[4];
    for (int j = 0; j < 5; ++j) dz0[j] = d[j] * sigm(zin[j]);
    for (int m = 0; m < 4; ++m) {
        float acc = 0.f;
        for (int j = 0; j < 5; ++j) acc += W0[m * 5 + j] * dz0[j];
        g[m] = acc;
    }
    float h_s = -(2.f * g[0] + g[1] - g[2] + 4.f * g[3]);
    ws[0] = e_id;
    ws[1] = h_s;
}

__device__ __forceinline__ float scalar_sample(const float* f,
        const float* W0, const float* b0, const float* Wh, const float* bh,
        const float* Wf, const float* bf, float e_id, float h_s) {
    float f0=f[0],f1=f[1],f2=f[2],f3=f[3],f4=f[4],f5=f[5],f6=f[6],f7=f[7],f8=f[8];
    float c00=f0*f0+f3*f3+f6*f6, c11=f1*f1+f4*f4+f7*f7, c22=f2*f2+f5*f5+f8*f8;
    float c01=f0*f1+f3*f4+f6*f7, c02=f0*f2+f3*f5+f6*f8, c12=f1*f2+f4*f5+f7*f8;
    float trC=c00+c11+c22;
    float trC2=c00*c00+c11*c11+c22*c22+2.f*(c01*c01+c02*c02+c12*c12);
    float I2=0.5f*(trC*trC-trC2);
    float J=f0*(f4*f8-f5*f7)-f1*(f3*f8-f5*f6)+f2*(f3*f7-f4*f6);
    float h[5];
    for (int j=0;j<5;++j)
        h[j]=spf(b0[j]+trC*W0[j]+J*(W0[5+j]-W0[10+j])+I2*W0[15+j]);
    for (int l=0;l<4;++l){
        float hn[5];
        for (int j=0;j<5;++j){
            float z=bh[l*5+j];
            for (int k=0;k<5;++k) z=fmaf(h[k],Wh[l*25+k*5+j],z);
            hn[j]=spf(z);
        }
        for (int j=0;j<5;++j) h[j]=hn[j];
    }
    float zf=bf[0];
    for (int k=0;k<5;++k) zf=fmaf(h[k],Wf[k],zf);
    return (spf(zf)-e_id)+h_s*0.5f*(trC-3.0f);
}

__global__ __launch_bounds__(256) void main_kernel(
        const float* __restrict__ F,
        const float* __restrict__ W0, const float* __restrict__ b0,
        const float* __restrict__ Wh, const float* __restrict__ bh,
        const float* __restrict__ Wf, const float* __restrict__ bf,
        const float* __restrict__ cs,   // [e_id, h_s]
        float* __restrict__ out, int n) {
    int t = blockIdx.x * blockDim.x + threadIdx.x;
    int i0 = t * 4;
    if (i0 >= n) return;
    if (i0 + 4 <= n) {
        // 4 samples: 36 contiguous floats, 16B-aligned (i0*36B = 144B*k).
        float q[36];
        const v4* src = (const v4*)(F + (size_t)i0 * 9);
        #pragma unroll
        for (int c = 0; c < 9; ++c) {
            v4 v = src[c];
            q[c*4+0]=v.x; q[c*4+1]=v.y; q[c*4+2]=v.z; q[c*4+3]=v.w;
        }
        v4 trC, J, I2;
        #pragma unroll
        for (int s = 0; s < 4; ++s) {
            const float* f = q + s * 9;
            float f0=f[0],f1=f[1],f2=f[2],f3=f[3],f4=f[4],f5=f[5],f6=f[6],f7=f[7],f8=f[8];
            float c00=f0*f0+f3*f3+f6*f6, c11=f1*f1+f4*f4+f7*f7, c22=f2*f2+f5*f5+f8*f8;
            float c01=f0*f1+f3*f4+f6*f7, c02=f0*f2+f3*f5+f6*f8, c12=f1*f2+f4*f5+f7*f8;
            float tc=c00+c11+c22;
            float trC2=c00*c00+c11*c11+c22*c22+2.f*(c01*c01+c02*c02+c12*c12);
            trC[s]=tc;
            I2[s]=0.5f*(tc*tc-trC2);
            J[s]=f0*(f4*f8-f5*f7)-f1*(f3*f8-f5*f6)+f2*(f3*f7-f4*f6);
        }
        // layer 0 (fold J and -J input rows)
        v4 h[5];
        #pragma unroll
        for (int j = 0; j < 5; ++j) {
            v4 z = splat(b0[j]);
            z = vfma(trC, W0[j], z);
            z = vfma(J, W0[5+j]-W0[10+j], z);
            z = vfma(I2, W0[15+j], z);
            h[j] = sp4(z);
        }
        // hidden layers; for l>=1, z is typically >> 17 where softplus(z)==z exactly in fp32
        #pragma unroll
        for (int l = 0; l < 4; ++l) {
            v4 z[5];
            #pragma unroll
            for (int j = 0; j < 5; ++j) {
                v4 zz = splat(bh[l*5+j]);
                #pragma unroll
                for (int k = 0; k < 5; ++k) zz = vfma(h[k], Wh[l*25+k*5+j], zz);
                z[j] = zz;
            }
            bool fast = false;
            if (l >= 1) {
                v4 m01; m01.x=fminf(z[0].x,z[1].x); m01.y=fminf(z[0].y,z[1].y);
                        m01.z=fminf(z[0].z,z[1].z); m01.w=fminf(z[0].w,z[1].w);
                #pragma unroll
                for (int j = 2; j < 5; ++j) {
                    m01.x=fminf(m01.x,z[j].x); m01.y=fminf(m01.y,z[j].y);
                    m01.z=fminf(m01.z,z[j].z); m01.w=fminf(m01.w,z[j].w);
                }
                float mm = fminf(fminf(m01.x,m01.y), fminf(m01.z,m01.w));
                fast = __all(mm > 17.0f);
            }
            if (fast) {
                #pragma unroll
                for (int j = 0; j < 5; ++j) h[j] = z[j];
            } else {
                #pragma unroll
                for (int j = 0; j < 5; ++j) h[j] = sp4(z[j]);
            }
        }
        v4 zf = splat(bf[0]);
        #pragma unroll
        for (int k = 0; k < 5; ++k) zf = vfma(h[k], Wf[k], zf);
        float mf = fminf(fminf(zf.x, zf.y), fminf(zf.z, zf.w));
        v4 e;
        if (__all(mf > 17.0f)) e = zf; else e = sp4(zf);
        float eid = cs[0], hs = cs[1];
        v4 res = (e - splat(eid)) + splat(hs * 0.5f) * (trC - splat(3.0f));
        *(v4*)(out + i0) = res;
    } else {
        float eid = cs[0], hs = cs[1];
        for (int s = 0; s < n - i0; ++s)
            out[i0 + s] = scalar_sample(F + (size_t)(i0 + s) * 9, W0, b0, Wh, bh, Wf, bf, eid, hs);
    }
}

extern "C" void kernel_launch(void* const* d_in, const int* in_sizes, int n_in,
                              void* d_out, int out_size, void* d_ws, size_t ws_size,
                              hipStream_t stream) {
    const float* F  = (const float*)d_in[0];
    const float* W0 = (const float*)d_in[1];
    const float* b0 = (const float*)d_in[2];
    const float* Wh = (const float*)d_in[3];
    const float* bh = (const float*)d_in[4];
    const float* Wf = (const float*)d_in[5];
    const float* bf = (const float*)d_in[6];
    float* out = (float*)d_out;
    float* ws  = (float*)d_ws;
    int n = in_sizes[0] / 9;
    setup_kernel<<<1, 64, 0, stream>>>(W0, b0, Wh, bh, Wf, bf, ws);
    int block = 256;
    int grid = (n / 4 + block - 1) / block;  // 4 samples per thread
    if (grid < 1) grid = 1;
    main_kernel<<<grid, block, 0, stream>>>(F, W0, b0, Wh, bh, Wf, bf, ws, out, n);
}